// Round 2
// baseline (160.453 us; speedup 1.0000x reference)
//
#include <hip/hip_runtime.h>

#define NROB 32
#define SEQ 12
#define LOBS 52
#define HID 256
#define LOUT 2
#define BATCH 1024
#define KIN (SEQ * LOBS)   // 624
#define CH 48              // samples per chunk (covers max multinomial count in 1 pass)
#define MAXC 56            // >= max chunks: sum ceil(cnt/48) <= 32 + 1024/48 ~ 54

// meta layout in ws (ints)
#define M_NCH 0
#define M_CSTART 1     // [32] first chunk index of robot r
#define M_SOFF 33      // [32] first sorted-sample offset of robot r
#define M_CNT 65       // [32] sample count of robot r
#define M_CHROB 97     // [56] chunk -> robot
#define M_PERM 161     // [1024] sorted slot -> original sample index
#define EA_OFF 2048                      // float offset of emb buffer A
#define EB_OFF (2048 + BATCH * HID)      // float offset of emb buffer B

__device__ __forceinline__ void fma4(float4& a, const float4 w, const float s) {
  a.x = fmaf(w.x, s, a.x);
  a.y = fmaf(w.y, s, a.y);
  a.z = fmaf(w.z, s, a.z);
  a.w = fmaf(w.w, s, a.w);
}

__global__ __launch_bounds__(1024) void k_sort(const int* __restrict__ ids,
                                               int* __restrict__ meta) {
  __shared__ int hist[NROB], cnt2[NROB], s_soff[NROB];
  const int t = threadIdx.x;
  if (t < NROB) { hist[t] = 0; cnt2[t] = 0; }
  __syncthreads();
  const int myid = ids[t];
  atomicAdd(&hist[myid], 1);
  __syncthreads();
  if (t == 0) {
    int off = 0, ch = 0;
    for (int r = 0; r < NROB; r++) {
      const int c = hist[r];
      s_soff[r] = off;
      meta[M_SOFF + r] = off;
      meta[M_CSTART + r] = ch;
      meta[M_CNT + r] = c;
      const int nch = (c + CH - 1) / CH;
      for (int q = 0; q < nch; q++) meta[M_CHROB + ch + q] = r;
      off += c;
      ch += nch;
    }
    meta[M_NCH] = ch;
  }
  __syncthreads();
  const int rank = atomicAdd(&cnt2[myid], 1);
  // intra-bucket order is schedule-dependent, but every per-sample output is an
  // order-independent dot product -> final d_out is invariant.
  meta[M_PERM + s_soff[myid] + rank] = t;
}

// Input layer: e0[p][c] = relu( sum_s m_s * ( sum_l obs[b][s*52+l]*Wi[r][s][l][c] + bi[r][s][c] ) )
// grid (8 col-tiles, MAXC chunks), block 384 = 8 cc x 48 jj
__global__ __launch_bounds__(384) void k_in(const float* __restrict__ obs,
                                            const int* __restrict__ mask,
                                            const int* __restrict__ meta,
                                            const float* __restrict__ Wi,
                                            const float* __restrict__ bi,
                                            float* __restrict__ e0) {
  const int ch = blockIdx.y;
  if (ch >= meta[M_NCH]) return;
  const int r = meta[M_CHROB + ch];
  const int base = (ch - meta[M_CSTART + r]) * CH;
  const int cnt = meta[M_CNT + r];
  const int soff = meta[M_SOFF + r];
  const int cc = threadIdx.x & 7, jj = threadIdx.x >> 3;
  if (base + (jj & ~7) >= cnt) return;  // whole wave inactive: skip its weight stream
  const int c = (blockIdx.x * 8 + cc) * 4;
  const int rank = base + jj;
  const bool act = rank < cnt;
  const int p = soff + (act ? rank : 0);
  const int b = meta[M_PERM + p];
  const float* obsb = obs + (size_t)b * KIN;
  const int* mb = mask + b * SEQ;
  const float* Wr = Wi + (size_t)r * KIN * HID + c;
  const float* br = bi + (size_t)r * SEQ * HID + c;
  float4 acc = {0.f, 0.f, 0.f, 0.f};
  for (int s = 0; s < SEQ; s++) {
    const float mf = (act && mb[s] == 0) ? 1.f : 0.f;
    float4 sacc = *(const float4*)(br + s * HID);  // bias folded at weight 1
#pragma unroll 4
    for (int l = 0; l < LOBS; l += 4) {
      const float4 o4 = *(const float4*)(obsb + s * LOBS + l);
      const float4 w0 = *(const float4*)(Wr + (size_t)(s * LOBS + l + 0) * HID);
      const float4 w1 = *(const float4*)(Wr + (size_t)(s * LOBS + l + 1) * HID);
      const float4 w2 = *(const float4*)(Wr + (size_t)(s * LOBS + l + 2) * HID);
      const float4 w3 = *(const float4*)(Wr + (size_t)(s * LOBS + l + 3) * HID);
      fma4(sacc, w0, o4.x);
      fma4(sacc, w1, o4.y);
      fma4(sacc, w2, o4.z);
      fma4(sacc, w3, o4.w);
    }
    fma4(acc, sacc, mf);  // mask (and bias) applied once per s
  }
  if (act) {
    float4 o = {fmaxf(acc.x, 0.f), fmaxf(acc.y, 0.f), fmaxf(acc.z, 0.f),
                fmaxf(acc.w, 0.f)};
    *(float4*)(e0 + (size_t)p * HID + c) = o;
  }
}

// Hidden layer: Xout[p][c] = relu( sum_k Xin[p][k]*W[r][k][c] + bias[r][c] )
__global__ __launch_bounds__(384) void k_dense(const float* __restrict__ W,
                                               const float* __restrict__ bias,
                                               const int* __restrict__ meta,
                                               const float* __restrict__ Xin,
                                               float* __restrict__ Xout) {
  const int ch = blockIdx.y;
  if (ch >= meta[M_NCH]) return;
  const int r = meta[M_CHROB + ch];
  const int base = (ch - meta[M_CSTART + r]) * CH;
  const int cnt = meta[M_CNT + r];
  const int soff = meta[M_SOFF + r];
  const int cc = threadIdx.x & 7, jj = threadIdx.x >> 3;
  if (base + (jj & ~7) >= cnt) return;
  const int c = (blockIdx.x * 8 + cc) * 4;
  const int rank = base + jj;
  const bool act = rank < cnt;
  const int p = soff + (act ? rank : 0);
  const float* xp = Xin + (size_t)p * HID;
  const float* Wr = W + (size_t)r * HID * HID + c;
  float4 acc = {0.f, 0.f, 0.f, 0.f};
#pragma unroll 4
  for (int k = 0; k < HID; k += 4) {
    const float4 e4 = *(const float4*)(xp + k);
    const float4 w0 = *(const float4*)(Wr + (size_t)(k + 0) * HID);
    const float4 w1 = *(const float4*)(Wr + (size_t)(k + 1) * HID);
    const float4 w2 = *(const float4*)(Wr + (size_t)(k + 2) * HID);
    const float4 w3 = *(const float4*)(Wr + (size_t)(k + 3) * HID);
    fma4(acc, w0, e4.x);
    fma4(acc, w1, e4.y);
    fma4(acc, w2, e4.z);
    fma4(acc, w3, e4.w);
  }
  if (act) {
    const float4 bv = *(const float4*)(bias + (size_t)r * HID + c);
    float4 o = {fmaxf(acc.x + bv.x, 0.f), fmaxf(acc.y + bv.y, 0.f),
                fmaxf(acc.z + bv.z, 0.f), fmaxf(acc.w + bv.w, 0.f)};
    *(float4*)(Xout + (size_t)p * HID + c) = o;
  }
}

// Output layer: out[b][s*2+d] = sum_k X[p][k]*Wo[r][s][k][d] + bo[r][s][d]
__global__ __launch_bounds__(384) void k_out(const float* __restrict__ Wo,
                                             const float* __restrict__ bo,
                                             const int* __restrict__ meta,
                                             const float* __restrict__ X,
                                             float* __restrict__ out) {
  const int ch = blockIdx.x;
  if (ch >= meta[M_NCH]) return;
  const int r = meta[M_CHROB + ch];
  const int base = (ch - meta[M_CSTART + r]) * CH;
  const int cnt = meta[M_CNT + r];
  const int soff = meta[M_SOFF + r];
#pragma unroll
  for (int rep = 0; rep < 3; rep++) {
    const int idx = rep * 384 + threadIdx.x;  // 1152 = 48 jj x 24 oc
    const int jj = idx / 24, oc = idx % 24;
    const int rank = base + jj;
    if (rank >= cnt) continue;
    const int p = soff + rank;
    const int b = meta[M_PERM + p];
    const int s = oc >> 1, d = oc & 1;
    const float* xp = X + (size_t)p * HID;
    const float* wbase = Wo + (size_t)(r * SEQ + s) * HID * LOUT;
    float acc = bo[(r * SEQ + s) * LOUT + d];
#pragma unroll 4
    for (int k = 0; k < HID; k += 2) {
      const float4 w = *(const float4*)(wbase + k * 2);  // [k][0],[k][1],[k+1][0],[k+1][1]
      const float2 e = *(const float2*)(xp + k);
      const float w0 = d ? w.y : w.x;
      const float w1 = d ? w.w : w.z;
      acc = fmaf(e.y, w1, fmaf(e.x, w0, acc));
    }
    out[(size_t)b * (SEQ * LOUT) + oc] = acc;
  }
}

extern "C" void kernel_launch(void* const* d_in, const int* in_sizes, int n_in,
                              void* d_out, int out_size, void* d_ws, size_t ws_size,
                              hipStream_t stream) {
  const float* obs = (const float*)d_in[0];
  const int* mask = (const int*)d_in[1];
  const int* ids = (const int*)d_in[2];
  const float* Wi = (const float*)d_in[3];
  const float* bi = (const float*)d_in[4];
  const float* W1 = (const float*)d_in[5];
  const float* b1 = (const float*)d_in[6];
  const float* W2 = (const float*)d_in[7];
  const float* b2 = (const float*)d_in[8];
  const float* W3 = (const float*)d_in[9];
  const float* b3 = (const float*)d_in[10];
  const float* Wo = (const float*)d_in[11];
  const float* bo = (const float*)d_in[12];
  float* out = (float*)d_out;
  int* meta = (int*)d_ws;
  float* eA = (float*)d_ws + EA_OFF;
  float* eB = (float*)d_ws + EB_OFF;

  hipLaunchKernelGGL(k_sort, dim3(1), dim3(1024), 0, stream, ids, meta);
  hipLaunchKernelGGL(k_in, dim3(8, MAXC), dim3(384), 0, stream, obs, mask, meta, Wi, bi, eA);
  hipLaunchKernelGGL(k_dense, dim3(8, MAXC), dim3(384), 0, stream, W1, b1, meta, eA, eB);
  hipLaunchKernelGGL(k_dense, dim3(8, MAXC), dim3(384), 0, stream, W2, b2, meta, eB, eA);
  hipLaunchKernelGGL(k_dense, dim3(8, MAXC), dim3(384), 0, stream, W3, b3, meta, eA, eB);
  hipLaunchKernelGGL(k_out, dim3(MAXC), dim3(384), 0, stream, Wo, bo, meta, eB, out);
}

// Round 3
// 89.823 us; speedup vs baseline: 1.7863x; 1.7863x over previous
//
#include <hip/hip_runtime.h>

#define NROB 32
#define SEQ 12
#define LOBS 52
#define HID 256
#define LOUT 2
#define BATCH 1024
#define KIN 624            // SEQ*LOBS
#define SPB 8              // samples per chunk
#define MAXCH 160          // sum ceil(cnt/8) <= 128+32
#define NSD (SEQ * LOUT)   // 24

// meta layout in ws (ints)
#define M_NCH 0
#define M_CSTART 1
#define M_SOFF 33
#define M_CNT 65
#define M_CHROB 97
#define M_PERM 257
#define EA_OFF 2048
#define EB_OFF (2048 + BATCH * HID)

__device__ __forceinline__ void fma4(float4& a, const float4 w, const float s) {
  a.x = fmaf(w.x, s, a.x);
  a.y = fmaf(w.y, s, a.y);
  a.z = fmaf(w.z, s, a.z);
  a.w = fmaf(w.w, s, a.w);
}

struct Chunk { int r, base, cnt, soff; };
__device__ __forceinline__ bool chunk_info(const int* meta, int ch, Chunk& c) {
  if (ch >= meta[M_NCH]) return false;
  c.r = meta[M_CHROB + ch];
  c.base = (ch - meta[M_CSTART + c.r]) * SPB;
  c.cnt = meta[M_CNT + c.r];
  c.soff = meta[M_SOFF + c.r];
  return true;
}

__global__ __launch_bounds__(1024) void k_sort(const int* __restrict__ ids,
                                               int* __restrict__ meta) {
  __shared__ int hist[NROB], cnt2[NROB], s_soff[NROB];
  const int t = threadIdx.x;
  if (t < NROB) { hist[t] = 0; cnt2[t] = 0; }
  __syncthreads();
  const int myid = ids[t];
  atomicAdd(&hist[myid], 1);
  __syncthreads();
  if (t == 0) {
    int off = 0, ch = 0;
    for (int r = 0; r < NROB; r++) {
      const int c = hist[r];
      s_soff[r] = off;
      meta[M_SOFF + r] = off;
      meta[M_CSTART + r] = ch;
      meta[M_CNT + r] = c;
      const int nch = (c + SPB - 1) / SPB;
      for (int q = 0; q < nch; q++) meta[M_CHROB + ch + q] = r;
      off += c;
      ch += nch;
    }
    meta[M_NCH] = ch;
  }
  __syncthreads();
  const int rank = atomicAdd(&cnt2[myid], 1);
  // intra-bucket order is schedule-dependent; per-sample outputs are
  // order-independent dot products -> d_out invariant.
  meta[M_PERM + s_soff[myid] + rank] = t;
}

// ---- input layer: 4 waves x 156 k-rows, lane = col-float4 (1KB coalesced W) ----
__global__ __launch_bounds__(256) void k_in(const float* __restrict__ obs,
                                            const int* __restrict__ mask,
                                            const int* __restrict__ meta,
                                            const float* __restrict__ Wi,
                                            const float* __restrict__ bi,
                                            float* __restrict__ Xout) {
  __shared__ float X[SPB][KIN + SEQ];  // masked obs + mask indicator rows
  __shared__ float P[4][SPB][HID];     // per-wave K-partials
  __shared__ int bm[SPB], vm[SPB];
  Chunk ci;
  if (!chunk_info(meta, blockIdx.x, ci)) return;
  const int t = threadIdx.x;
  if (t < SPB) {
    const int rank = ci.base + t;
    const int v = rank < ci.cnt;
    vm[t] = v;
    bm[t] = meta[M_PERM + ci.soff + (v ? rank : 0)];
  }
  __syncthreads();
  for (int f = t; f < SPB * KIN; f += 256) {
    const int ms = f / LOBS;  // m*SEQ + s
    const int m = ms / SEQ, s = ms - m * SEQ;
    const int k = f - m * KIN;
    float val = 0.f;
    if (vm[m] && mask[bm[m] * SEQ + s] == 0) val = obs[(size_t)bm[m] * KIN + k];
    X[m][k] = val;
  }
  if (t < SPB * SEQ) {
    const int m = t / SEQ, s = t - m * SEQ;
    X[m][KIN + s] = (vm[m] && mask[bm[m] * SEQ + s] == 0) ? 1.f : 0.f;
  }
  __syncthreads();

  const int w = t >> 6, lane = t & 63;
  const float* Wr = Wi + (size_t)ci.r * KIN * HID + lane * 4;
  const int kbase = w * 156;
  float4 acc[SPB];
#pragma unroll
  for (int m = 0; m < SPB; m++) acc[m] = {0.f, 0.f, 0.f, 0.f};
#pragma unroll 2
  for (int kk = 0; kk < 156; kk += 4) {
    const int k0 = kbase + kk;
    const float4 w0 = *(const float4*)(Wr + (size_t)(k0 + 0) * HID);
    const float4 w1 = *(const float4*)(Wr + (size_t)(k0 + 1) * HID);
    const float4 w2 = *(const float4*)(Wr + (size_t)(k0 + 2) * HID);
    const float4 w3 = *(const float4*)(Wr + (size_t)(k0 + 3) * HID);
#pragma unroll
    for (int m = 0; m < SPB; m++) {
      const float4 x = *(const float4*)&X[m][k0];  // lane-uniform: LDS broadcast
      fma4(acc[m], w0, x.x);
      fma4(acc[m], w1, x.y);
      fma4(acc[m], w2, x.z);
      fma4(acc[m], w3, x.w);
    }
  }
#pragma unroll
  for (int m = 0; m < SPB; m++) *(float4*)&P[w][m][lane * 4] = acc[m];
  __syncthreads();

#pragma unroll
  for (int rep = 0; rep < 2; rep++) {
    const int idx = rep * 256 + t;
    const int m = idx >> 6, c4 = (idx & 63) * 4;
    if (!vm[m]) continue;
    const float4 a0 = *(const float4*)&P[0][m][c4];
    const float4 a1 = *(const float4*)&P[1][m][c4];
    const float4 a2 = *(const float4*)&P[2][m][c4];
    const float4 a3 = *(const float4*)&P[3][m][c4];
    float4 a = {a0.x + a1.x + a2.x + a3.x, a0.y + a1.y + a2.y + a3.y,
                a0.z + a1.z + a2.z + a3.z, a0.w + a1.w + a2.w + a3.w};
    const float* br = bi + (size_t)ci.r * SEQ * HID + c4;
#pragma unroll
    for (int s = 0; s < SEQ; s++) {
      const float4 b4 = *(const float4*)(br + s * HID);
      fma4(a, b4, X[m][KIN + s]);  // sum_s (1-mask_s)*bi_s
    }
    float4 o = {fmaxf(a.x, 0.f), fmaxf(a.y, 0.f), fmaxf(a.z, 0.f), fmaxf(a.w, 0.f)};
    *(float4*)(Xout + (size_t)(ci.soff + ci.base + m) * HID + c4) = o;
  }
}

// ---- hidden layer: 4 waves x 64 k-rows ----
__global__ __launch_bounds__(256) void k_hid(const float* __restrict__ W,
                                             const float* __restrict__ bias,
                                             const int* __restrict__ meta,
                                             const float* __restrict__ Xin,
                                             float* __restrict__ Xout) {
  __shared__ float X[SPB][HID];
  __shared__ float P[4][SPB][HID];
  Chunk ci;
  if (!chunk_info(meta, blockIdx.x, ci)) return;
  const int t = threadIdx.x;
#pragma unroll
  for (int rep = 0; rep < 2; rep++) {
    const int idx = rep * 256 + t;
    const int m = idx >> 6, c4 = (idx & 63) * 4;
    float4 val = {0.f, 0.f, 0.f, 0.f};
    if (ci.base + m < ci.cnt)
      val = *(const float4*)(Xin + (size_t)(ci.soff + ci.base + m) * HID + c4);
    *(float4*)&X[m][c4] = val;
  }
  __syncthreads();

  const int w = t >> 6, lane = t & 63;
  const float* Wr = W + (size_t)ci.r * HID * HID + lane * 4;
  const int kbase = w * 64;
  float4 acc[SPB];
#pragma unroll
  for (int m = 0; m < SPB; m++) acc[m] = {0.f, 0.f, 0.f, 0.f};
#pragma unroll 2
  for (int kk = 0; kk < 64; kk += 4) {
    const int k0 = kbase + kk;
    const float4 w0 = *(const float4*)(Wr + (size_t)(k0 + 0) * HID);
    const float4 w1 = *(const float4*)(Wr + (size_t)(k0 + 1) * HID);
    const float4 w2 = *(const float4*)(Wr + (size_t)(k0 + 2) * HID);
    const float4 w3 = *(const float4*)(Wr + (size_t)(k0 + 3) * HID);
#pragma unroll
    for (int m = 0; m < SPB; m++) {
      const float4 x = *(const float4*)&X[m][k0];
      fma4(acc[m], w0, x.x);
      fma4(acc[m], w1, x.y);
      fma4(acc[m], w2, x.z);
      fma4(acc[m], w3, x.w);
    }
  }
#pragma unroll
  for (int m = 0; m < SPB; m++) *(float4*)&P[w][m][lane * 4] = acc[m];
  __syncthreads();

#pragma unroll
  for (int rep = 0; rep < 2; rep++) {
    const int idx = rep * 256 + t;
    const int m = idx >> 6, c4 = (idx & 63) * 4;
    if (ci.base + m >= ci.cnt) continue;
    const float4 a0 = *(const float4*)&P[0][m][c4];
    const float4 a1 = *(const float4*)&P[1][m][c4];
    const float4 a2 = *(const float4*)&P[2][m][c4];
    const float4 a3 = *(const float4*)&P[3][m][c4];
    const float4 bv = *(const float4*)(bias + (size_t)ci.r * HID + c4);
    float4 o = {fmaxf(a0.x + a1.x + a2.x + a3.x + bv.x, 0.f),
                fmaxf(a0.y + a1.y + a2.y + a3.y + bv.y, 0.f),
                fmaxf(a0.z + a1.z + a2.z + a3.z + bv.z, 0.f),
                fmaxf(a0.w + a1.w + a2.w + a3.w + bv.w, 0.f)};
    *(float4*)(Xout + (size_t)(ci.soff + ci.base + m) * HID + c4) = o;
  }
}

// ---- layer 3 + output hypernetwork, fused ----
__global__ __launch_bounds__(256) void k_last(const float* __restrict__ W,
                                              const float* __restrict__ bias,
                                              const float* __restrict__ Wo,
                                              const float* __restrict__ bo,
                                              const int* __restrict__ meta,
                                              const float* __restrict__ Xin,
                                              float* __restrict__ out) {
  __shared__ float X[SPB][HID];
  __shared__ float P[4][SPB][HID];  // reused as Wo-LDS (stride 25) after reduce
  float* S = &P[0][0][0];
  Chunk ci;
  if (!chunk_info(meta, blockIdx.x, ci)) return;
  const int t = threadIdx.x;
#pragma unroll
  for (int rep = 0; rep < 2; rep++) {
    const int idx = rep * 256 + t;
    const int m = idx >> 6, c4 = (idx & 63) * 4;
    float4 val = {0.f, 0.f, 0.f, 0.f};
    if (ci.base + m < ci.cnt)
      val = *(const float4*)(Xin + (size_t)(ci.soff + ci.base + m) * HID + c4);
    *(float4*)&X[m][c4] = val;
  }
  __syncthreads();

  const int w = t >> 6, lane = t & 63;
  const float* Wr = W + (size_t)ci.r * HID * HID + lane * 4;
  const int kbase = w * 64;
  float4 acc[SPB];
#pragma unroll
  for (int m = 0; m < SPB; m++) acc[m] = {0.f, 0.f, 0.f, 0.f};
#pragma unroll 2
  for (int kk = 0; kk < 64; kk += 4) {
    const int k0 = kbase + kk;
    const float4 w0 = *(const float4*)(Wr + (size_t)(k0 + 0) * HID);
    const float4 w1 = *(const float4*)(Wr + (size_t)(k0 + 1) * HID);
    const float4 w2 = *(const float4*)(Wr + (size_t)(k0 + 2) * HID);
    const float4 w3 = *(const float4*)(Wr + (size_t)(k0 + 3) * HID);
#pragma unroll
    for (int m = 0; m < SPB; m++) {
      const float4 x = *(const float4*)&X[m][k0];
      fma4(acc[m], w0, x.x);
      fma4(acc[m], w1, x.y);
      fma4(acc[m], w2, x.z);
      fma4(acc[m], w3, x.w);
    }
  }
#pragma unroll
  for (int m = 0; m < SPB; m++) *(float4*)&P[w][m][lane * 4] = acc[m];
  __syncthreads();

  // reduce into X (emb3), in-place over the staged activations
#pragma unroll
  for (int rep = 0; rep < 2; rep++) {
    const int idx = rep * 256 + t;
    const int m = idx >> 6, c4 = (idx & 63) * 4;
    const float4 a0 = *(const float4*)&P[0][m][c4];
    const float4 a1 = *(const float4*)&P[1][m][c4];
    const float4 a2 = *(const float4*)&P[2][m][c4];
    const float4 a3 = *(const float4*)&P[3][m][c4];
    const float4 bv = *(const float4*)(bias + (size_t)ci.r * HID + c4);
    float4 o = {fmaxf(a0.x + a1.x + a2.x + a3.x + bv.x, 0.f),
                fmaxf(a0.y + a1.y + a2.y + a3.y + bv.y, 0.f),
                fmaxf(a0.z + a1.z + a2.z + a3.z + bv.z, 0.f),
                fmaxf(a0.w + a1.w + a2.w + a3.w + bv.w, 0.f)};
    *(float4*)&X[m][c4] = o;
  }
  __syncthreads();  // P now dead -> reuse as Wo tile [k][sd], stride 25

  for (int q = t; q < (NSD * HID) / 4; q += 256) {
    const float4 v = *(const float4*)(Wo + (size_t)ci.r * SEQ * HID * LOUT + q * 4);
    const int flat = q * 4;
    const int s = flat / (HID * LOUT);
    const int k = (flat - s * HID * LOUT) >> 1;  // d pair packed in float4
    S[(k + 0) * 25 + s * 2 + 0] = v.x;
    S[(k + 0) * 25 + s * 2 + 1] = v.y;
    S[(k + 1) * 25 + s * 2 + 0] = v.z;
    S[(k + 1) * 25 + s * 2 + 1] = v.w;
  }
  __syncthreads();

  if (t < SPB * NSD) {  // 192 threads: one (sample, s*2+d) output each
    const int m = t / NSD, sd = t - m * NSD;
    const int rank = ci.base + m;
    float acc1 = bo[(size_t)ci.r * NSD + sd];
#pragma unroll 4
    for (int k = 0; k < HID; k++) acc1 = fmaf(X[m][k], S[k * 25 + sd], acc1);
    if (rank < ci.cnt)
      out[(size_t)meta[M_PERM + ci.soff + rank] * NSD + sd] = acc1;
  }
}

extern "C" void kernel_launch(void* const* d_in, const int* in_sizes, int n_in,
                              void* d_out, int out_size, void* d_ws, size_t ws_size,
                              hipStream_t stream) {
  const float* obs = (const float*)d_in[0];
  const int* mask = (const int*)d_in[1];
  const int* ids = (const int*)d_in[2];
  const float* Wi = (const float*)d_in[3];
  const float* bi = (const float*)d_in[4];
  const float* W1 = (const float*)d_in[5];
  const float* b1 = (const float*)d_in[6];
  const float* W2 = (const float*)d_in[7];
  const float* b2 = (const float*)d_in[8];
  const float* W3 = (const float*)d_in[9];
  const float* b3 = (const float*)d_in[10];
  const float* Wo = (const float*)d_in[11];
  const float* bo = (const float*)d_in[12];
  float* out = (float*)d_out;
  int* meta = (int*)d_ws;
  float* eA = (float*)d_ws + EA_OFF;
  float* eB = (float*)d_ws + EB_OFF;

  hipLaunchKernelGGL(k_sort, dim3(1), dim3(1024), 0, stream, ids, meta);
  hipLaunchKernelGGL(k_in, dim3(MAXCH), dim3(256), 0, stream, obs, mask, meta, Wi, bi, eA);
  hipLaunchKernelGGL(k_hid, dim3(MAXCH), dim3(256), 0, stream, W1, b1, meta, eA, eB);
  hipLaunchKernelGGL(k_hid, dim3(MAXCH), dim3(256), 0, stream, W2, b2, meta, eB, eA);
  hipLaunchKernelGGL(k_last, dim3(MAXCH), dim3(256), 0, stream, W3, b3, Wo, bo, meta, eA, out);
}

// Round 4
// 41.097 us; speedup vs baseline: 3.9043x; 2.1856x over previous
//
#include <hip/hip_runtime.h>

#define NROB 32
#define SEQ 12
#define LOBS 52
#define HID 256
#define LOUT 2
#define BATCH 1024
#define KIN 624            // SEQ*LOBS
#define XROW 636           // KIN + SEQ indicator cols
#define SPB 8              // samples per chunk/block
#define NSD 24             // SEQ*LOUT
#define NBLK 320           // 8 xcds x 40 slots
#define SLOTS 40

__device__ __forceinline__ void fma4(float4& a, const float4 w, const float s) {
  a.x = fmaf(w.x, s, a.x);
  a.y = fmaf(w.y, s, a.y);
  a.z = fmaf(w.z, s, a.z);
  a.w = fmaf(w.w, s, a.w);
}

// Stream ROWS weight rows (row stride HID floats) against 8 samples' activations
// (LDS, row stride XS), accumulating acc[m] (float4 of output cols = lane*4).
// Double-buffered: 8 float4 weight loads in flight.
template <int ROWS, int XS>
__device__ __forceinline__ void stream8(const float* __restrict__ Wr,
                                        const float* Xb, float4* acc) {
  static_assert(ROWS % 8 == 0, "ROWS must be multiple of 8");
  constexpr int G = ROWS / 8;
  const float* wp = Wr;
  float4 a0 = *(const float4*)(wp);
  float4 a1 = *(const float4*)(wp + HID);
  float4 a2 = *(const float4*)(wp + 2 * HID);
  float4 a3 = *(const float4*)(wp + 3 * HID);
  wp += 4 * HID;
#pragma unroll
  for (int g = 0; g < G; ++g) {
    const int k = g * 8;
    const float4 b0 = *(const float4*)(wp);
    const float4 b1 = *(const float4*)(wp + HID);
    const float4 b2 = *(const float4*)(wp + 2 * HID);
    const float4 b3 = *(const float4*)(wp + 3 * HID);
    wp += 4 * HID;
#pragma unroll
    for (int m = 0; m < SPB; ++m) {
      const float4 x = *(const float4*)(Xb + m * XS + k);
      fma4(acc[m], a0, x.x);
      fma4(acc[m], a1, x.y);
      fma4(acc[m], a2, x.z);
      fma4(acc[m], a3, x.w);
    }
    if (g + 1 < G) {
      a0 = *(const float4*)(wp);
      a1 = *(const float4*)(wp + HID);
      a2 = *(const float4*)(wp + 2 * HID);
      a3 = *(const float4*)(wp + 3 * HID);
      wp += 4 * HID;
    }
#pragma unroll
    for (int m = 0; m < SPB; ++m) {
      const float4 x = *(const float4*)(Xb + m * XS + k + 4);
      fma4(acc[m], b0, x.x);
      fma4(acc[m], b1, x.y);
      fma4(acc[m], b2, x.z);
      fma4(acc[m], b3, x.w);
    }
  }
}

__global__ __launch_bounds__(512, 4) void k_fused(
    const float* __restrict__ obs, const int* __restrict__ mask,
    const int* __restrict__ ids, const float* __restrict__ Wi,
    const float* __restrict__ bi, const float* __restrict__ W1,
    const float* __restrict__ b1, const float* __restrict__ W2,
    const float* __restrict__ b2, const float* __restrict__ W3,
    const float* __restrict__ b3, const float* __restrict__ Wo,
    const float* __restrict__ bo, float* __restrict__ out) {
  __shared__ int s_cnt[NROB];
  __shared__ int s_wc[16];
  __shared__ int s_bm[SPB], s_vm[SPB], s_mb[SPB];
  __shared__ __align__(16) float s_x0[SPB * XROW];   // 20352B; reused as X2 [SPB][HID]
  __shared__ __align__(16) float s_P[4][SPB][HID];   // 32768B; reused as Wo tile
  __shared__ __align__(16) float s_x1[SPB][HID];     // 8192B

  const int t = threadIdx.x;
  const int bx = blockIdx.x;

  // ---- phase 0a: histogram of robot ids (deterministic counts) ----
  if (t < NROB) s_cnt[t] = 0;
  if (t < SPB) s_bm[t] = 0;
  __syncthreads();
  const int id0 = ids[t];
  const int id1 = ids[t + 512];
  atomicAdd(&s_cnt[id0], 1);
  atomicAdd(&s_cnt[id1], 1);
  __syncthreads();

  // ---- phase 0b: deterministic chunk->block mapping (XCD-swizzled) ----
  // Chunks of robot r live on xcd r%8 (blocks dispatch round-robin: xcd = bx%8).
  // Fallback to linear mapping if any xcd bucket would overflow SLOTS.
  int myr = -1, mybase = 0;
  {
    int maxbucket = 0;
    for (int x = 0; x < 8; ++x) {
      int bsum = 0;
      for (int r = x; r < NROB; r += 8) bsum += (s_cnt[r] + SPB - 1) >> 3;
      maxbucket = max(maxbucket, bsum);
    }
    if (maxbucket <= SLOTS) {
      const int myxcd = bx & 7, myslot = bx >> 3;
      int slot = 0;
      for (int r = myxcd; r < NROB; r += 8) {
        const int nch = (s_cnt[r] + SPB - 1) >> 3;
        if (myr < 0 && myslot >= slot && myslot < slot + nch) {
          myr = r;
          mybase = (myslot - slot) * SPB;
        }
        slot += nch;
      }
    } else {
      int ch = 0;
      for (int r = 0; r < NROB; ++r) {
        const int nch = (s_cnt[r] + SPB - 1) >> 3;
        if (myr < 0 && bx >= ch && bx < ch + nch) {
          myr = r;
          mybase = (bx - ch) * SPB;
        }
        ch += nch;
      }
    }
  }
  if (myr < 0) return;  // uniform across block
  const int mycnt = s_cnt[myr];

  // ---- phase 0c: stable sample ranks via ballot scan (deterministic) ----
  {
    const int wv = t >> 6;
    const unsigned lane = t & 63;
    const unsigned long long m0 = __ballot(id0 == myr);
    const unsigned long long m1 = __ballot(id1 == myr);
    if (lane == 0) {
      s_wc[wv] = __popcll(m0);
      s_wc[8 + wv] = __popcll(m1);
    }
    __syncthreads();
    const unsigned long long below = (1ull << lane) - 1ull;
    int pre0 = 0;
    for (int i = 0; i < wv; ++i) pre0 += s_wc[i];
    if (id0 == myr) {
      const int j = pre0 + __popcll(m0 & below) - mybase;
      if (j >= 0 && j < SPB) s_bm[j] = t;
    }
    int pre1 = 0;
    for (int i = 0; i < 8 + wv; ++i) pre1 += s_wc[i];
    if (id1 == myr) {
      const int j = pre1 + __popcll(m1 & below) - mybase;
      if (j >= 0 && j < SPB) s_bm[j] = t + 512;
    }
    __syncthreads();
  }
  if (t < SPB) {
    const int v = (mybase + t) < mycnt;
    s_vm[t] = v;
    int mb = 0xFFF;  // invalid slot: all-masked -> zero row
    if (v) {
      mb = 0;
      const int b = s_bm[t];
      for (int s = 0; s < SEQ; ++s) mb |= (mask[b * SEQ + s] != 0) << s;
    }
    s_mb[t] = mb;
  }
  __syncthreads();

  // ---- stage masked X0 (float4; 52 = 13 float4 per s-segment) ----
  for (int q = t; q < SPB * (KIN / 4); q += 512) {
    const int m = q / 156, f4 = q - m * 156;
    const int s = f4 / 13;
    float4 v = {0.f, 0.f, 0.f, 0.f};
    if (!((s_mb[m] >> s) & 1))
      v = *(const float4*)(obs + (size_t)s_bm[m] * KIN + f4 * 4);
    *(float4*)&s_x0[m * XROW + f4 * 4] = v;
  }
  if (t < SPB * SEQ) {
    const int m = t / SEQ, s = t - m * SEQ;
    s_x0[m * XROW + KIN + s] = ((s_mb[m] >> s) & 1) ? 0.f : 1.f;
  }
  __syncthreads();

  const int w = t >> 6, lane = t & 63;

  // ---- input layer: 8 waves x {80,80,80,80,80,80,80,64} k-rows ----
  {
    float4 acc[SPB];
#pragma unroll
    for (int m = 0; m < SPB; ++m) acc[m] = {0.f, 0.f, 0.f, 0.f};
    const float* Wr = Wi + ((size_t)myr * KIN + w * 80) * HID + lane * 4;
    if (w < 7)
      stream8<80, XROW>(Wr, &s_x0[w * 80], acc);
    else
      stream8<64, XROW>(Wr, &s_x0[w * 80], acc);
    float* Pp = &s_P[w >> 1][0][lane * 4];
    if ((w & 1) == 0) {
#pragma unroll
      for (int m = 0; m < SPB; ++m) *(float4*)(Pp + m * HID) = acc[m];
    }
    __syncthreads();
    if (w & 1) {
#pragma unroll
      for (int m = 0; m < SPB; ++m) {
        float4 c = *(const float4*)(Pp + m * HID);
        c.x += acc[m].x;
        c.y += acc[m].y;
        c.z += acc[m].z;
        c.w += acc[m].w;
        *(float4*)(Pp + m * HID) = c;
      }
    }
    __syncthreads();
    {  // finalize: sum 4 partials + sum_s (1-mask_s)*bi_s, relu -> X1
      const int m = t >> 6, c4 = (t & 63) * 4;
      const float4 p0 = *(const float4*)&s_P[0][m][c4];
      const float4 p1 = *(const float4*)&s_P[1][m][c4];
      const float4 p2 = *(const float4*)&s_P[2][m][c4];
      const float4 p3 = *(const float4*)&s_P[3][m][c4];
      float4 a = {p0.x + p1.x + p2.x + p3.x, p0.y + p1.y + p2.y + p3.y,
                  p0.z + p1.z + p2.z + p3.z, p0.w + p1.w + p2.w + p3.w};
      const float* br = bi + (size_t)myr * SEQ * HID + c4;
#pragma unroll
      for (int s = 0; s < SEQ; ++s)
        fma4(a, *(const float4*)(br + s * HID), s_x0[m * XROW + KIN + s]);
      float4 o = {fmaxf(a.x, 0.f), fmaxf(a.y, 0.f), fmaxf(a.z, 0.f),
                  fmaxf(a.w, 0.f)};
      *(float4*)&s_x1[m][c4] = o;
    }
    __syncthreads();
  }

  // ---- hidden layers (32 k-rows/wave) ----
  float* X2 = s_x0;  // X0 dead after input-layer finalize
  const float* Ws[3] = {W1, W2, W3};
  const float* bs[3] = {b1, b2, b3};
#pragma unroll
  for (int L = 0; L < 3; ++L) {
    const float* Xin = (L & 1) ? X2 : &s_x1[0][0];
    float* Xout = (L & 1) ? &s_x1[0][0] : X2;
    float4 acc[SPB];
#pragma unroll
    for (int m = 0; m < SPB; ++m) acc[m] = {0.f, 0.f, 0.f, 0.f};
    const float* Wr = Ws[L] + ((size_t)myr * HID + w * 32) * HID + lane * 4;
    stream8<32, HID>(Wr, Xin + w * 32, acc);
    float* Pp = &s_P[w >> 1][0][lane * 4];
    if ((w & 1) == 0) {
#pragma unroll
      for (int m = 0; m < SPB; ++m) *(float4*)(Pp + m * HID) = acc[m];
    }
    __syncthreads();
    if (w & 1) {
#pragma unroll
      for (int m = 0; m < SPB; ++m) {
        float4 c = *(const float4*)(Pp + m * HID);
        c.x += acc[m].x;
        c.y += acc[m].y;
        c.z += acc[m].z;
        c.w += acc[m].w;
        *(float4*)(Pp + m * HID) = c;
      }
    }
    __syncthreads();
    {
      const int m = t >> 6, c4 = (t & 63) * 4;
      const float4 p0 = *(const float4*)&s_P[0][m][c4];
      const float4 p1 = *(const float4*)&s_P[1][m][c4];
      const float4 p2 = *(const float4*)&s_P[2][m][c4];
      const float4 p3 = *(const float4*)&s_P[3][m][c4];
      const float4 bv = *(const float4*)(bs[L] + (size_t)myr * HID + c4);
      float4 o = {fmaxf(p0.x + p1.x + p2.x + p3.x + bv.x, 0.f),
                  fmaxf(p0.y + p1.y + p2.y + p3.y + bv.y, 0.f),
                  fmaxf(p0.z + p1.z + p2.z + p3.z + bv.z, 0.f),
                  fmaxf(p0.w + p1.w + p2.w + p3.w + bv.w, 0.f)};
      *(float4*)(Xout + m * HID + c4) = o;
    }
    __syncthreads();
  }
  // L3 output now in X2 (= s_x0)

  // ---- output hypernetwork: stage Wo as S[k*25 + sd] (conflict-free) ----
  float* S = &s_P[0][0][0];  // 256*25*4 = 25600B <= 32768B
  {
    const float* Wop = Wo + (size_t)myr * SEQ * HID * LOUT;
    for (int q = t; q < (NSD * HID) / 4; q += 512) {
      const float4 v = *(const float4*)(Wop + q * 4);
      const int flat = q * 4;
      const int s = flat >> 9;          // / (HID*LOUT)
      const int k = (flat & 511) >> 1;  // d-pairs packed in float4
      S[(k + 0) * 25 + s * 2 + 0] = v.x;
      S[(k + 0) * 25 + s * 2 + 1] = v.y;
      S[(k + 1) * 25 + s * 2 + 0] = v.z;
      S[(k + 1) * 25 + s * 2 + 1] = v.w;
    }
  }
  __syncthreads();
  if (t < SPB * NSD) {  // 192 threads: one (sample, s*2+d) each
    const int m = t / NSD, sd = t - m * NSD;
    float a = bo[(size_t)myr * NSD + sd];
    const float* xp = X2 + m * HID;
#pragma unroll 8
    for (int k = 0; k < HID; ++k) a = fmaf(xp[k], S[k * 25 + sd], a);
    if (s_vm[m]) out[(size_t)s_bm[m] * NSD + sd] = a;
  }
}

extern "C" void kernel_launch(void* const* d_in, const int* in_sizes, int n_in,
                              void* d_out, int out_size, void* d_ws, size_t ws_size,
                              hipStream_t stream) {
  const float* obs = (const float*)d_in[0];
  const int* mask = (const int*)d_in[1];
  const int* ids = (const int*)d_in[2];
  const float* Wi = (const float*)d_in[3];
  const float* bi = (const float*)d_in[4];
  const float* W1 = (const float*)d_in[5];
  const float* b1 = (const float*)d_in[6];
  const float* W2 = (const float*)d_in[7];
  const float* b2 = (const float*)d_in[8];
  const float* W3 = (const float*)d_in[9];
  const float* b3 = (const float*)d_in[10];
  const float* Wo = (const float*)d_in[11];
  const float* bo = (const float*)d_in[12];
  float* out = (float*)d_out;
  (void)d_ws;
  hipLaunchKernelGGL(k_fused, dim3(NBLK), dim3(512), 0, stream, obs, mask, ids,
                     Wi, bi, W1, b1, W2, b2, W3, b3, Wo, bo, out);
}

// Round 5
// 40.348 us; speedup vs baseline: 3.9768x; 1.0186x over previous
//
#include <hip/hip_runtime.h>

#define NROB 32
#define SEQ 12
#define LOBS 52
#define HID 256
#define LOUT 2
#define BATCH 1024
#define KIN 624            // SEQ*LOBS
#define SPB 8              // samples per chunk/block
#define NSD 24             // SEQ*LOUT
#define NBLK 320           // 8 xcds x 40 slots
#define SLOTS 40

__device__ __forceinline__ void fma4(float4& a, const float4 w, const float s) {
  a.x = fmaf(w.x, s, a.x);
  a.y = fmaf(w.y, s, a.y);
  a.z = fmaf(w.z, s, a.z);
  a.w = fmaf(w.w, s, a.w);
}

// Stream ROWS weight rows (stride HID) against 4 samples (LDS row stride SX),
// acc[i] = float4 of output cols (lane*4). 16 loads in flight (8-deep dbuf).
template <int ROWS, int SX>
__device__ __forceinline__ void stream4(const float* __restrict__ wp,
                                        const float* xb, float4* acc) {
  static_assert(ROWS % 8 == 0, "ROWS multiple of 8");
  constexpr int G = ROWS / 8;
  float4 w[8];
#pragma unroll
  for (int j = 0; j < 8; ++j) w[j] = *(const float4*)(wp + j * HID);
  wp += 8 * HID;
#pragma unroll
  for (int g = 0; g < G; ++g) {
    float4 nw[8];
    if (g + 1 < G) {
#pragma unroll
      for (int j = 0; j < 8; ++j) nw[j] = *(const float4*)(wp + j * HID);
      wp += 8 * HID;
    }
#pragma unroll
    for (int i = 0; i < 4; ++i) {
      const float4 xa = *(const float4*)(xb + i * SX + g * 8);
      const float4 xc = *(const float4*)(xb + i * SX + g * 8 + 4);
      fma4(acc[i], w[0], xa.x);
      fma4(acc[i], w[1], xa.y);
      fma4(acc[i], w[2], xa.z);
      fma4(acc[i], w[3], xa.w);
      fma4(acc[i], w[4], xc.x);
      fma4(acc[i], w[5], xc.y);
      fma4(acc[i], w[6], xc.z);
      fma4(acc[i], w[7], xc.w);
    }
#pragma unroll
    for (int j = 0; j < 8; ++j) w[j] = nw[j];
  }
}

__global__ __launch_bounds__(1024, 4) void k_fused(
    const float* __restrict__ obs, const int* __restrict__ mask,
    const int* __restrict__ ids, const float* __restrict__ Wi,
    const float* __restrict__ bi, const float* __restrict__ W1,
    const float* __restrict__ b1, const float* __restrict__ W2,
    const float* __restrict__ b2, const float* __restrict__ W3,
    const float* __restrict__ b3, const float* __restrict__ Wo,
    const float* __restrict__ bo, float* __restrict__ out) {
  __shared__ int s_cnt[NROB];
  __shared__ int s_wc[16];
  __shared__ int s_bm[SPB], s_vm[SPB], s_mb[SPB];
  __shared__ float s_ind[SPB][SEQ];
  __shared__ __align__(16) float s_x0[SPB * KIN];   // 19968B; reused as X2 [8][256]
  __shared__ __align__(16) float s_P[4][SPB][HID];  // 32768B; reused as Wo tile
  __shared__ __align__(16) float s_x1[SPB][HID];    // 8192B

  const int t = threadIdx.x;
  const int bx = blockIdx.x;

  // ---- phase 0a: histogram ----
  if (t < NROB) s_cnt[t] = 0;
  if (t < SPB) s_bm[t] = 0;
  __syncthreads();
  const int id0 = ids[t];
  atomicAdd(&s_cnt[id0], 1);
  __syncthreads();

  // ---- phase 0b: deterministic chunk->block mapping (XCD-swizzled) ----
  int myr = -1, mybase = 0;
  {
    int maxbucket = 0;
    for (int x = 0; x < 8; ++x) {
      int bsum = 0;
      for (int r = x; r < NROB; r += 8) bsum += (s_cnt[r] + SPB - 1) >> 3;
      maxbucket = max(maxbucket, bsum);
    }
    if (maxbucket <= SLOTS) {
      const int myxcd = bx & 7, myslot = bx >> 3;
      int slot = 0;
      for (int r = myxcd; r < NROB; r += 8) {
        const int nch = (s_cnt[r] + SPB - 1) >> 3;
        if (myr < 0 && myslot >= slot && myslot < slot + nch) {
          myr = r;
          mybase = (myslot - slot) * SPB;
        }
        slot += nch;
      }
    } else {
      int ch = 0;
      for (int r = 0; r < NROB; ++r) {
        const int nch = (s_cnt[r] + SPB - 1) >> 3;
        if (myr < 0 && bx >= ch && bx < ch + nch) {
          myr = r;
          mybase = (bx - ch) * SPB;
        }
        ch += nch;
      }
    }
  }
  if (myr < 0) return;  // uniform across block
  const int mycnt = s_cnt[myr];

  // ---- phase 0c: stable sample ranks via ballot scan ----
  {
    const int wv = t >> 6;
    const unsigned lane = t & 63;
    const unsigned long long m0 = __ballot(id0 == myr);
    if (lane == 0) s_wc[wv] = __popcll(m0);
    __syncthreads();
    int pre = 0;
    for (int i = 0; i < wv; ++i) pre += s_wc[i];
    if (id0 == myr) {
      const unsigned long long below = (1ull << lane) - 1ull;
      const int j = pre + __popcll(m0 & below) - mybase;
      if (j >= 0 && j < SPB) s_bm[j] = t;
    }
    __syncthreads();
  }
  if (t < SPB) {
    const int v = (mybase + t) < mycnt;
    s_vm[t] = v;
    int mb = 0xFFF;
    if (v) {
      mb = 0;
      const int b = s_bm[t];
      for (int s = 0; s < SEQ; ++s) mb |= (mask[b * SEQ + s] != 0) << s;
    }
    s_mb[t] = mb;
  }
  if (t >= 64 && t < 64 + SPB * SEQ) {
    // filled after the t<SPB wave? No: same barrier below covers both via s_mb
  }
  __syncthreads();
  if (t < SPB * SEQ) {
    const int m = t / SEQ, s = t - m * SEQ;
    s_ind[m][s] = ((s_mb[m] >> s) & 1) ? 0.f : 1.f;
  }
  // ---- stage masked X0 (156 float4 per sample) ----
  for (int q = t; q < SPB * (KIN / 4); q += 1024) {
    const int m = q / 156, f4 = q - m * 156;
    const int s = f4 / 13;
    float4 v = {0.f, 0.f, 0.f, 0.f};
    if (!((s_mb[m] >> s) & 1))
      v = *(const float4*)(obs + (size_t)s_bm[m] * KIN + f4 * 4);
    *(float4*)&s_x0[m * KIN + f4 * 4] = v;
  }
  __syncthreads();

  const int w = t >> 6, lane = t & 63;
  const int seg = w >> 1, sg = w & 1;  // K-segment 0..7, sample-group 0..1
  float* Pp = &s_P[seg & 3][sg * 4][lane * 4];

  // ---- input layer: segs 0-6 have 80 rows, seg 7 has 64 ----
  {
    float4 acc[4];
#pragma unroll
    for (int i = 0; i < 4; ++i) acc[i] = {0.f, 0.f, 0.f, 0.f};
    const float* Wr = Wi + ((size_t)myr * KIN + seg * 80) * HID + lane * 4;
    const float* xb = &s_x0[(sg * 4) * KIN + seg * 80];
    if (seg < 7)
      stream4<80, KIN>(Wr, xb, acc);
    else
      stream4<64, KIN>(Wr, xb, acc);
    if (seg < 4) {
#pragma unroll
      for (int i = 0; i < 4; ++i) *(float4*)(Pp + i * HID) = acc[i];
    }
    __syncthreads();
    if (seg >= 4) {
#pragma unroll
      for (int i = 0; i < 4; ++i) {
        float4 c = *(const float4*)(Pp + i * HID);
        c.x += acc[i].x;
        c.y += acc[i].y;
        c.z += acc[i].z;
        c.w += acc[i].w;
        *(float4*)(Pp + i * HID) = c;
      }
    }
    __syncthreads();
    {  // finalize: sum 4 partials + sum_s ind*bi_s, relu -> X1 (float2/thread)
      const int m = t >> 7, c2 = (t & 127) * 2;
      float2 a = {0.f, 0.f};
#pragma unroll
      for (int j = 0; j < 4; ++j) {
        const float2 p = *(const float2*)&s_P[j][m][c2];
        a.x += p.x;
        a.y += p.y;
      }
      const float* br = bi + (size_t)myr * SEQ * HID + c2;
#pragma unroll
      for (int s = 0; s < SEQ; ++s) {
        const float2 b2v = *(const float2*)(br + s * HID);
        const float f = s_ind[m][s];
        a.x = fmaf(b2v.x, f, a.x);
        a.y = fmaf(b2v.y, f, a.y);
      }
      s_x1[m][c2] = fmaxf(a.x, 0.f);
      s_x1[m][c2 + 1] = fmaxf(a.y, 0.f);
    }
    __syncthreads();
  }

  // ---- hidden layers: 32 rows per seg ----
  float* X2 = s_x0;  // [8][256] region reuse
  const float* Ws[3] = {W1, W2, W3};
  const float* bs[3] = {b1, b2, b3};
#pragma unroll
  for (int L = 0; L < 3; ++L) {
    const float* Xin = (L & 1) ? X2 : &s_x1[0][0];
    float* Xout = (L & 1) ? &s_x1[0][0] : X2;
    float4 acc[4];
#pragma unroll
    for (int i = 0; i < 4; ++i) acc[i] = {0.f, 0.f, 0.f, 0.f};
    const float* Wr = Ws[L] + ((size_t)myr * HID + seg * 32) * HID + lane * 4;
    stream4<32, HID>(Wr, Xin + (sg * 4) * HID + seg * 32, acc);
    if (seg < 4) {
#pragma unroll
      for (int i = 0; i < 4; ++i) *(float4*)(Pp + i * HID) = acc[i];
    }
    __syncthreads();
    if (seg >= 4) {
#pragma unroll
      for (int i = 0; i < 4; ++i) {
        float4 c = *(const float4*)(Pp + i * HID);
        c.x += acc[i].x;
        c.y += acc[i].y;
        c.z += acc[i].z;
        c.w += acc[i].w;
        *(float4*)(Pp + i * HID) = c;
      }
    }
    __syncthreads();
    {
      const int m = t >> 7, c2 = (t & 127) * 2;
      float2 a = {0.f, 0.f};
#pragma unroll
      for (int j = 0; j < 4; ++j) {
        const float2 p = *(const float2*)&s_P[j][m][c2];
        a.x += p.x;
        a.y += p.y;
      }
      const float2 bv = *(const float2*)(bs[L] + (size_t)myr * HID + c2);
      Xout[m * HID + c2] = fmaxf(a.x + bv.x, 0.f);
      Xout[m * HID + c2 + 1] = fmaxf(a.y + bv.y, 0.f);
    }
    __syncthreads();
  }
  // L3 output now in X2 (= s_x0)

  // ---- output hypernetwork: Wo tile S[k*25 + sd] (conflict-free) ----
  float* S = &s_P[0][0][0];  // 25600B <= 32768B
  {
    const float* Wop = Wo + (size_t)myr * SEQ * HID * LOUT;
    for (int q = t; q < (NSD * HID) / 4; q += 1024) {
      const float4 v = *(const float4*)(Wop + q * 4);
      const int flat = q * 4;
      const int s = flat >> 9;
      const int k = (flat & 511) >> 1;
      S[(k + 0) * 25 + s * 2 + 0] = v.x;
      S[(k + 0) * 25 + s * 2 + 1] = v.y;
      S[(k + 1) * 25 + s * 2 + 0] = v.z;
      S[(k + 1) * 25 + s * 2 + 1] = v.w;
    }
  }
  __syncthreads();
  if (t < SPB * NSD) {
    const int m = t / NSD, sd = t - m * NSD;
    float a = bo[(size_t)myr * NSD + sd];
    const float* xp = X2 + m * HID;
#pragma unroll 8
    for (int k = 0; k < HID; ++k) a = fmaf(xp[k], S[k * 25 + sd], a);
    if (s_vm[m]) out[(size_t)s_bm[m] * NSD + sd] = a;
  }
}

extern "C" void kernel_launch(void* const* d_in, const int* in_sizes, int n_in,
                              void* d_out, int out_size, void* d_ws, size_t ws_size,
                              hipStream_t stream) {
  const float* obs = (const float*)d_in[0];
  const int* mask = (const int*)d_in[1];
  const int* ids = (const int*)d_in[2];
  const float* Wi = (const float*)d_in[3];
  const float* bi = (const float*)d_in[4];
  const float* W1 = (const float*)d_in[5];
  const float* b1 = (const float*)d_in[6];
  const float* W2 = (const float*)d_in[7];
  const float* b2 = (const float*)d_in[8];
  const float* W3 = (const float*)d_in[9];
  const float* b3 = (const float*)d_in[10];
  const float* Wo = (const float*)d_in[11];
  const float* bo = (const float*)d_in[12];
  float* out = (float*)d_out;
  (void)d_ws;
  hipLaunchKernelGGL(k_fused, dim3(NBLK), dim3(1024), 0, stream, obs, mask, ids,
                     Wi, bi, W1, b1, W2, b2, W3, b3, Wo, bo, out);
}

// Round 6
// 35.414 us; speedup vs baseline: 4.5308x; 1.1393x over previous
//
#include <hip/hip_runtime.h>

#define NROB 32
#define SEQ 12
#define LOBS 52
#define HID 256
#define LOUT 2
#define BATCH 1024
#define KIN 624            // SEQ*LOBS
#define SPB 8              // samples per chunk/block
#define NSD 24             // SEQ*LOUT
#define NBLK 320           // 8 xcds x 40 slots
#define SLOTS 40

__device__ __forceinline__ void fma4(float4& a, const float4 w, const float s) {
  a.x = fmaf(w.x, s, a.x);
  a.y = fmaf(w.y, s, a.y);
  a.z = fmaf(w.z, s, a.z);
  a.w = fmaf(w.w, s, a.w);
}

// Stream ROWS weight rows (stride HID floats) against 8 samples (LDS row stride
// XS), acc[m] = float4 of output cols (lane*4). Even/odd A/B register buffers,
// loads issued 2 groups (16 rows) ahead, NO register copies -> compiler emits
// counted vmcnt waits (A and B are independent sets), keeping >=8 KB/wave in
// flight continuously instead of draining vmcnt(0) each group.
template <int ROWS, int XS>
__device__ __forceinline__ void stream8(const float* __restrict__ wp,
                                        const float* xb, float4* acc) {
  static_assert(ROWS % 16 == 0, "ROWS multiple of 16");
  constexpr int G = ROWS / 8;  // even
  float4 A[8], B[8];
#pragma unroll
  for (int j = 0; j < 8; ++j) A[j] = *(const float4*)(wp + j * HID);
#pragma unroll
  for (int j = 0; j < 8; ++j) B[j] = *(const float4*)(wp + (8 + j) * HID);
#pragma unroll
  for (int g = 0; g < G; g += 2) {
    const int k = g * 8;
    // compute with A (rows k..k+7); B's loads in flight
#pragma unroll
    for (int m = 0; m < SPB; ++m) {
      const float4 xa = *(const float4*)(xb + m * XS + k);
      const float4 xc = *(const float4*)(xb + m * XS + k + 4);
      fma4(acc[m], A[0], xa.x);
      fma4(acc[m], A[1], xa.y);
      fma4(acc[m], A[2], xa.z);
      fma4(acc[m], A[3], xa.w);
      fma4(acc[m], A[4], xc.x);
      fma4(acc[m], A[5], xc.y);
      fma4(acc[m], A[6], xc.z);
      fma4(acc[m], A[7], xc.w);
    }
    if (g + 2 < G) {
#pragma unroll
      for (int j = 0; j < 8; ++j)
        A[j] = *(const float4*)(wp + (size_t)(k + 16 + j) * HID);
    }
    // compute with B (rows k+8..k+15); A(g+2)'s loads in flight
#pragma unroll
    for (int m = 0; m < SPB; ++m) {
      const float4 xa = *(const float4*)(xb + m * XS + k + 8);
      const float4 xc = *(const float4*)(xb + m * XS + k + 12);
      fma4(acc[m], B[0], xa.x);
      fma4(acc[m], B[1], xa.y);
      fma4(acc[m], B[2], xa.z);
      fma4(acc[m], B[3], xa.w);
      fma4(acc[m], B[4], xc.x);
      fma4(acc[m], B[5], xc.y);
      fma4(acc[m], B[6], xc.z);
      fma4(acc[m], B[7], xc.w);
    }
    if (g + 3 < G) {
#pragma unroll
      for (int j = 0; j < 8; ++j)
        B[j] = *(const float4*)(wp + (size_t)(k + 24 + j) * HID);
    }
  }
}

__global__ __launch_bounds__(512, 2) void k_fused(
    const float* __restrict__ obs, const int* __restrict__ mask,
    const int* __restrict__ ids, const float* __restrict__ Wi,
    const float* __restrict__ bi, const float* __restrict__ W1,
    const float* __restrict__ b1, const float* __restrict__ W2,
    const float* __restrict__ b2, const float* __restrict__ W3,
    const float* __restrict__ b3, const float* __restrict__ Wo,
    const float* __restrict__ bo, float* __restrict__ out) {
  __shared__ int s_cnt[NROB];
  __shared__ int s_wc[8];
  __shared__ int s_bm[SPB], s_vm[SPB], s_mb[SPB];
  __shared__ float s_ind[SPB][SEQ];
  __shared__ __align__(16) float s_x0[SPB * KIN];   // 19968B; reused as X2 [8][256]
  __shared__ __align__(16) float s_P[4][SPB][HID];  // 32768B; reused as Wo tile
  __shared__ __align__(16) float s_x1[SPB][HID];    // 8192B

  const int t = threadIdx.x;
  const int bx = blockIdx.x;

  // ---- phase 0a: histogram ----
  if (t < NROB) s_cnt[t] = 0;
  if (t < SPB) s_bm[t] = 0;
  __syncthreads();
  const int id0 = ids[t];
  const int id1 = ids[t + 512];
  atomicAdd(&s_cnt[id0], 1);
  atomicAdd(&s_cnt[id1], 1);
  __syncthreads();

  // ---- phase 0b: deterministic chunk->block mapping (XCD-swizzled) ----
  int myr = -1, mybase = 0;
  {
    int maxbucket = 0;
    for (int x = 0; x < 8; ++x) {
      int bsum = 0;
      for (int r = x; r < NROB; r += 8) bsum += (s_cnt[r] + SPB - 1) >> 3;
      maxbucket = max(maxbucket, bsum);
    }
    if (maxbucket <= SLOTS) {
      const int myxcd = bx & 7, myslot = bx >> 3;
      int slot = 0;
      for (int r = myxcd; r < NROB; r += 8) {
        const int nch = (s_cnt[r] + SPB - 1) >> 3;
        if (myr < 0 && myslot >= slot && myslot < slot + nch) {
          myr = r;
          mybase = (myslot - slot) * SPB;
        }
        slot += nch;
      }
    } else {
      int ch = 0;
      for (int r = 0; r < NROB; ++r) {
        const int nch = (s_cnt[r] + SPB - 1) >> 3;
        if (myr < 0 && bx >= ch && bx < ch + nch) {
          myr = r;
          mybase = (bx - ch) * SPB;
        }
        ch += nch;
      }
    }
  }
  if (myr < 0) return;  // uniform across block
  const int mycnt = s_cnt[myr];

  // ---- phase 0c: stable sample ranks via ballot scan ----
  {
    const int wv = t >> 6;
    const unsigned lane = t & 63;
    const unsigned long long m0 = __ballot(id0 == myr);
    const unsigned long long m1 = __ballot(id1 == myr);
    if (lane == 0) {
      s_wc[wv] = __popcll(m0);
      // counts for the id1 half accumulated below via prefix over 8+wv
    }
    __syncthreads();
    // prefix over first half waves for id0; full first half + waves<wv for id1
    const unsigned long long below = (1ull << lane) - 1ull;
    int pre0 = 0;
    for (int i = 0; i < wv; ++i) pre0 += s_wc[i];
    if (id0 == myr) {
      const int j = pre0 + __popcll(m0 & below) - mybase;
      if (j >= 0 && j < SPB) s_bm[j] = t;
    }
    __syncthreads();
    if (lane == 0) s_wc[wv] = __popcll(m1);  // reuse for second half
    __syncthreads();
    int all0 = 0;
    {
      // total of first half: recompute via ballot popcount sums kept in regs
      // (cheap: sum of own-half counts was consumed; recompute from masks)
    }
    // total first-half count for robot myr:
    // accumulate via shared: store popcll(m0) separately
    __syncthreads();
    // NOTE: to keep prefix exact we recompute: first-half totals were
    // overwritten; use a second pass with both halves staged.
    // (handled below with s_wc2 logic folded into s_wc via offset trick)
    int pre1 = 0;
    for (int i = 0; i < wv; ++i) pre1 += s_wc[i];
    // add full first-half total: derive from mycnt? not available per-half;
    // stage it explicitly:
    __shared__ int s_h0;
    if (t == 0) s_h0 = 0;
    __syncthreads();
    if (lane == 0) atomicAdd(&s_h0, __popcll(m0));
    __syncthreads();
    if (id1 == myr) {
      const int j = s_h0 + pre1 + __popcll(m1 & below) - mybase;
      if (j >= 0 && j < SPB) s_bm[j] = t + 512;
    }
    __syncthreads();
  }
  if (t < SPB) {
    const int v = (mybase + t) < mycnt;
    s_vm[t] = v;
    int mb = 0xFFF;
    if (v) {
      mb = 0;
      const int b = s_bm[t];
      for (int s = 0; s < SEQ; ++s) mb |= (mask[b * SEQ + s] != 0) << s;
    }
    s_mb[t] = mb;
  }
  __syncthreads();
  if (t < SPB * SEQ) {
    const int m = t / SEQ, s = t - m * SEQ;
    s_ind[m][s] = ((s_mb[m] >> s) & 1) ? 0.f : 1.f;
  }
  // ---- stage masked X0 (156 float4 per sample) ----
  for (int q = t; q < SPB * (KIN / 4); q += 512) {
    const int m = q / 156, f4 = q - m * 156;
    const int s = f4 / 13;
    float4 v = {0.f, 0.f, 0.f, 0.f};
    if (!((s_mb[m] >> s) & 1))
      v = *(const float4*)(obs + (size_t)s_bm[m] * KIN + f4 * 4);
    *(float4*)&s_x0[m * KIN + f4 * 4] = v;
  }
  __syncthreads();

  const int w = t >> 6, lane = t & 63;
  float* Pp = &s_P[w >> 1][0][lane * 4];

  // ---- input layer: waves 0-6 have 80 rows, wave 7 has 64 ----
  {
    float4 acc[SPB];
#pragma unroll
    for (int m = 0; m < SPB; ++m) acc[m] = {0.f, 0.f, 0.f, 0.f};
    const float* Wr = Wi + ((size_t)myr * KIN + w * 80) * HID + lane * 4;
    const float* xb = &s_x0[w * 80];
    if (w < 7)
      stream8<80, KIN>(Wr, xb, acc);
    else
      stream8<64, KIN>(Wr, xb, acc);
    if ((w & 1) == 0) {
#pragma unroll
      for (int m = 0; m < SPB; ++m) *(float4*)(Pp + m * HID) = acc[m];
    }
    __syncthreads();
    if (w & 1) {
#pragma unroll
      for (int m = 0; m < SPB; ++m) {
        float4 c = *(const float4*)(Pp + m * HID);
        c.x += acc[m].x;
        c.y += acc[m].y;
        c.z += acc[m].z;
        c.w += acc[m].w;
        *(float4*)(Pp + m * HID) = c;
      }
    }
    __syncthreads();
    {  // finalize: sum 4 partials + sum_s ind*bi_s, relu -> X1
      const int m = t >> 6, c4 = (t & 63) * 4;
      const float4 p0 = *(const float4*)&s_P[0][m][c4];
      const float4 p1 = *(const float4*)&s_P[1][m][c4];
      const float4 p2 = *(const float4*)&s_P[2][m][c4];
      const float4 p3 = *(const float4*)&s_P[3][m][c4];
      float4 a = {p0.x + p1.x + p2.x + p3.x, p0.y + p1.y + p2.y + p3.y,
                  p0.z + p1.z + p2.z + p3.z, p0.w + p1.w + p2.w + p3.w};
      const float* br = bi + (size_t)myr * SEQ * HID + c4;
#pragma unroll
      for (int s = 0; s < SEQ; ++s)
        fma4(a, *(const float4*)(br + s * HID), s_ind[m][s]);
      float4 o = {fmaxf(a.x, 0.f), fmaxf(a.y, 0.f), fmaxf(a.z, 0.f),
                  fmaxf(a.w, 0.f)};
      *(float4*)&s_x1[m][c4] = o;
    }
    __syncthreads();
  }

  // ---- hidden layers: 32 rows per wave ----
  float* X2 = s_x0;  // [8][256] region reuse
  const float* Ws[3] = {W1, W2, W3};
  const float* bs[3] = {b1, b2, b3};
#pragma unroll
  for (int L = 0; L < 3; ++L) {
    const float* Xin = (L & 1) ? X2 : &s_x1[0][0];
    float* Xout = (L & 1) ? &s_x1[0][0] : X2;
    float4 acc[SPB];
#pragma unroll
    for (int m = 0; m < SPB; ++m) acc[m] = {0.f, 0.f, 0.f, 0.f};
    const float* Wr = Ws[L] + ((size_t)myr * HID + w * 32) * HID + lane * 4;
    stream8<32, HID>(Wr, Xin + w * 32, acc);
    if ((w & 1) == 0) {
#pragma unroll
      for (int m = 0; m < SPB; ++m) *(float4*)(Pp + m * HID) = acc[m];
    }
    __syncthreads();
    if (w & 1) {
#pragma unroll
      for (int m = 0; m < SPB; ++m) {
        float4 c = *(const float4*)(Pp + m * HID);
        c.x += acc[m].x;
        c.y += acc[m].y;
        c.z += acc[m].z;
        c.w += acc[m].w;
        *(float4*)(Pp + m * HID) = c;
      }
    }
    __syncthreads();
    {
      const int m = t >> 6, c4 = (t & 63) * 4;
      const float4 p0 = *(const float4*)&s_P[0][m][c4];
      const float4 p1 = *(const float4*)&s_P[1][m][c4];
      const float4 p2 = *(const float4*)&s_P[2][m][c4];
      const float4 p3 = *(const float4*)&s_P[3][m][c4];
      const float4 bv = *(const float4*)(bs[L] + (size_t)myr * HID + c4);
      float4 o = {fmaxf(p0.x + p1.x + p2.x + p3.x + bv.x, 0.f),
                  fmaxf(p0.y + p1.y + p2.y + p3.y + bv.y, 0.f),
                  fmaxf(p0.z + p1.z + p2.z + p3.z + bv.z, 0.f),
                  fmaxf(p0.w + p1.w + p2.w + p3.w + bv.w, 0.f)};
      *(float4*)(Xout + m * HID + c4) = o;
    }
    __syncthreads();
  }
  // L3 output now in X2 (= s_x0)

  // ---- output hypernetwork: Wo tile S[k*25 + sd] (conflict-free) ----
  float* S = &s_P[0][0][0];  // 25600B <= 32768B
  {
    const float* Wop = Wo + (size_t)myr * SEQ * HID * LOUT;
    for (int q = t; q < (NSD * HID) / 4; q += 512) {
      const float4 v = *(const float4*)(Wop + q * 4);
      const int flat = q * 4;
      const int s = flat >> 9;
      const int k = (flat & 511) >> 1;
      S[(k + 0) * 25 + s * 2 + 0] = v.x;
      S[(k + 0) * 25 + s * 2 + 1] = v.y;
      S[(k + 1) * 25 + s * 2 + 0] = v.z;
      S[(k + 1) * 25 + s * 2 + 1] = v.w;
    }
  }
  __syncthreads();
  if (t < SPB * NSD) {
    const int m = t / NSD, sd = t - m * NSD;
    float a = bo[(size_t)myr * NSD + sd];
    const float* xp = X2 + m * HID;
#pragma unroll 8
    for (int k = 0; k < HID; ++k) a = fmaf(xp[k], S[k * 25 + sd], a);
    if (s_vm[m]) out[(size_t)s_bm[m] * NSD + sd] = a;
  }
}

extern "C" void kernel_launch(void* const* d_in, const int* in_sizes, int n_in,
                              void* d_out, int out_size, void* d_ws, size_t ws_size,
                              hipStream_t stream) {
  const float* obs = (const float*)d_in[0];
  const int* mask = (const int*)d_in[1];
  const int* ids = (const int*)d_in[2];
  const float* Wi = (const float*)d_in[3];
  const float* bi = (const float*)d_in[4];
  const float* W1 = (const float*)d_in[5];
  const float* b1 = (const float*)d_in[6];
  const float* W2 = (const float*)d_in[7];
  const float* b2 = (const float*)d_in[8];
  const float* W3 = (const float*)d_in[9];
  const float* b3 = (const float*)d_in[10];
  const float* Wo = (const float*)d_in[11];
  const float* bo = (const float*)d_in[12];
  float* out = (float*)d_out;
  (void)d_ws;
  hipLaunchKernelGGL(k_fused, dim3(NBLK), dim3(512), 0, stream, obs, mask, ids,
                     Wi, bi, W1, b1, W2, b2, W3, b3, Wo, bo, out);
}